// Round 1
// baseline (435.432 us; speedup 1.0000x reference)
//
#include <hip/hip_runtime.h>
#include <hip/hip_bf16.h>

// Problem: B=4, H=16, S=2048, D=64
//   scores = QK^T / 8; scores = mask ? -1e9 : scores
//   O = scores @ V;  out = log_softmax(O, axis=-1)  [over D=64]
// Fused flash-style kernel: per block = one (b,h,qtile of 64 rows).
// bf16 MFMA for both matmuls (error ~3e7 << threshold ~5e9).

#define Bq 4
#define Hq 16
#define Sq 2048
#define Dq 64
#define QT 64
#define KT 128
#define NEGV (-1e9f)

typedef __attribute__((ext_vector_type(8))) short bf16x8;
typedef __attribute__((ext_vector_type(4))) float f32x4;

__device__ inline unsigned cvt_bf16(float f) {
    unsigned u = __builtin_bit_cast(unsigned, f);
    u += 0x7FFFu + ((u >> 16) & 1u);   // RNE (no NaNs in this problem)
    return u >> 16;
}

__global__ __launch_bounds__(256, 2)
void attn_kernel(const float* __restrict__ Q, const float* __restrict__ K,
                 const float* __restrict__ V, const int* __restrict__ M,
                 float* __restrict__ Out) {
    // LDS tiles (bf16 as ushort), rows padded to break bank-conflict strides,
    // 16B-aligned for ds_read_b128 fragment loads.
    __shared__ __attribute__((aligned(16))) unsigned short sQ[QT][72];        // 9.2 KB
    __shared__ __attribute__((aligned(16))) unsigned short sK[KT][72];        // 18.4 KB
    __shared__ __attribute__((aligned(16))) unsigned short sVt[Dq][KT + 8];   // 17.4 KB (V transposed: [d][k])
    __shared__ __attribute__((aligned(16))) unsigned short sS[QT][KT + 8];    // 17.4 KB
    // total ~61 KB -> 2 blocks/CU

    const int tid  = threadIdx.x;
    const int wave = tid >> 6;
    const int lane = tid & 63;
    const int quad = lane >> 4;
    const int l16  = lane & 15;

    const int bid = blockIdx.x;
    const int h  = bid & 15;          // h innermost: 16 consecutive blocks share the mask tile
    const int qt = (bid >> 4) & 31;
    const int b  = bid >> 9;
    const int bh = b * Hq + h;
    const int q0 = qt * QT;

    const float* Qb = Q + (size_t)(bh * Sq + q0) * Dq;
    const float* Kb = K + (size_t)bh * Sq * Dq;
    const float* Vb = V + (size_t)bh * Sq * Dq;
    const int*   Mb = M + (size_t)(b * Sq + q0) * Sq;

    // ---- stage Q tile (scaled by 1/sqrt(64) = 0.125) ----
#pragma unroll
    for (int i = 0; i < 4; i++) {
        int e = tid + i * 256;            // 0..1023 float4s over 64x64
        int row = e >> 4, c4 = e & 15;
        const float4 v = *(const float4*)(Qb + row * Dq + c4 * 4);
        uint2 pk;
        pk.x = cvt_bf16(v.x * 0.125f) | (cvt_bf16(v.y * 0.125f) << 16);
        pk.y = cvt_bf16(v.z * 0.125f) | (cvt_bf16(v.w * 0.125f) << 16);
        *(uint2*)&sQ[row][c4 * 4] = pk;
    }

    f32x4 Oacc[4];
#pragma unroll
    for (int t = 0; t < 4; t++) Oacc[t] = (f32x4){0.f, 0.f, 0.f, 0.f};

    for (int ki = 0; ki < Sq / KT; ki++) {
        const int k0 = ki * KT;
        __syncthreads();   // previous iteration's LDS reads done before overwrite

        // ---- stage K tile [128x64] and V tile transposed -> sVt[d][k] ----
#pragma unroll
        for (int i = 0; i < 8; i++) {
            int e = tid + i * 256;        // 0..2047 float4s over 128x64
            int row = e >> 4, c4 = e & 15;
            const float4 kv = *(const float4*)(Kb + (size_t)(k0 + row) * Dq + c4 * 4);
            uint2 pk;
            pk.x = cvt_bf16(kv.x) | (cvt_bf16(kv.y) << 16);
            pk.y = cvt_bf16(kv.z) | (cvt_bf16(kv.w) << 16);
            *(uint2*)&sK[row][c4 * 4] = pk;
            const float4 vv = *(const float4*)(Vb + (size_t)(k0 + row) * Dq + c4 * 4);
            int d = c4 * 4;
            sVt[d + 0][row] = (unsigned short)cvt_bf16(vv.x);
            sVt[d + 1][row] = (unsigned short)cvt_bf16(vv.y);
            sVt[d + 2][row] = (unsigned short)cvt_bf16(vv.z);
            sVt[d + 3][row] = (unsigned short)cvt_bf16(vv.w);
        }
        __syncthreads();

        // ---- MFMA1: S[64x128] = Qs @ K^T ; wave w owns rows 16w..16w+15 ----
        // A frag: A[m=l16][k=quad*8+j] -> sQ[16w+l16][quad*8 + half*32]
        // B frag: B[k=d][n=kk]=K[kk][d] -> sK[16j+l16][quad*8 + half*32]
        const bf16x8 aQ0 = *(const bf16x8*)&sQ[wave * 16 + l16][quad * 8];
        const bf16x8 aQ1 = *(const bf16x8*)&sQ[wave * 16 + l16][quad * 8 + 32];
        f32x4 Sacc[8];
#pragma unroll
        for (int j = 0; j < 8; j++) {
            const bf16x8 bK0 = *(const bf16x8*)&sK[j * 16 + l16][quad * 8];
            const bf16x8 bK1 = *(const bf16x8*)&sK[j * 16 + l16][quad * 8 + 32];
            f32x4 acc = (f32x4){0.f, 0.f, 0.f, 0.f};
            acc = __builtin_amdgcn_mfma_f32_16x16x32_bf16(aQ0, bK0, acc, 0, 0, 0);
            acc = __builtin_amdgcn_mfma_f32_16x16x32_bf16(aQ1, bK1, acc, 0, 0, 0);
            Sacc[j] = acc;
        }

        // ---- mask (C layout: col=l16, row=quad*4+r), cvt bf16, write S to LDS ----
#pragma unroll
        for (int j = 0; j < 8; j++) {
            const int kk = k0 + j * 16 + l16;
#pragma unroll
            for (int r = 0; r < 4; r++) {
                const int qrow = wave * 16 + quad * 4 + r;
                const int m = Mb[(size_t)qrow * Sq + kk];
                const float val = m ? NEGV : Sacc[j][r];
                sS[qrow][j * 16 + l16] = (unsigned short)cvt_bf16(val);
            }
        }
        __syncthreads();

        // ---- MFMA2: O[64x64] += S @ V ----
        // A frag: S[q=l16][k] -> sS[16w+l16][ks*32 + quad*8]
        // B frag: B[k][n=d]=V[k][d] -> sVt[16t+l16][ks*32 + quad*8]
#pragma unroll
        for (int ks = 0; ks < 4; ks++) {
            const bf16x8 aS = *(const bf16x8*)&sS[wave * 16 + l16][ks * 32 + quad * 8];
#pragma unroll
            for (int t = 0; t < 4; t++) {
                const bf16x8 bV = *(const bf16x8*)&sVt[t * 16 + l16][ks * 32 + quad * 8];
                Oacc[t] = __builtin_amdgcn_mfma_f32_16x16x32_bf16(aS, bV, Oacc[t], 0, 0, 0);
            }
        }
    }

    // ---- epilogue: log_softmax over D=64 per row ----
    // Lane holds rows q=16w+quad*4+r (r=0..3), cols d=16t+l16 (t=0..3).
    // Row reduction = across the 16 lanes of the quad (xor 1,2,4,8) x 4 tiles.
    float lse[4];
#pragma unroll
    for (int r = 0; r < 4; r++) {
        float mx = fmaxf(fmaxf(Oacc[0][r], Oacc[1][r]), fmaxf(Oacc[2][r], Oacc[3][r]));
#pragma unroll
        for (int off = 1; off < 16; off <<= 1)
            mx = fmaxf(mx, __shfl_xor(mx, off, 64));
        float s = 0.f;
#pragma unroll
        for (int t = 0; t < 4; t++) s += __expf(Oacc[t][r] - mx);
#pragma unroll
        for (int off = 1; off < 16; off <<= 1)
            s += __shfl_xor(s, off, 64);
        lse[r] = mx + __logf(s);
    }

    float* Ob = Out + (size_t)(bh * Sq + q0 + wave * 16) * Dq;
#pragma unroll
    for (int r = 0; r < 4; r++) {
#pragma unroll
        for (int t = 0; t < 4; t++) {
            Ob[(quad * 4 + r) * Dq + t * 16 + l16] = Oacc[t][r] - lse[r];
        }
    }
}

extern "C" void kernel_launch(void* const* d_in, const int* in_sizes, int n_in,
                              void* d_out, int out_size, void* d_ws, size_t ws_size,
                              hipStream_t stream) {
    const float* Q = (const float*)d_in[0];
    const float* K = (const float*)d_in[1];
    const float* V = (const float*)d_in[2];
    const int*   M = (const int*)d_in[3];
    float* Out = (float*)d_out;

    dim3 grid(Bq * Hq * (Sq / QT));   // 2048 blocks
    dim3 block(256);
    attn_kernel<<<grid, block, 0, stream>>>(Q, K, V, M, Out);
}

// Round 3
// 340.400 us; speedup vs baseline: 1.2792x; 1.2792x over previous
//
#include <hip/hip_runtime.h>
#include <hip/hip_bf16.h>

// B=4, H=16, S=2048, D=64
//   S = mask ? -1e9 : QK^T/8 ; O = S@V ; out = log_softmax(O, dim=-1)
// v2.1: 32x32x16 MFMA, register-blocked (64 q-rows/wave), S^T trick so the
// S round-trip is wave-private (no barrier), all LDS patterns at bank floor.
// (v2 fix: manual RNE bf16 pack — __hip_bfloat162 is not bit_cast-able.)

typedef __attribute__((ext_vector_type(8))) short bf16x8;
typedef __attribute__((ext_vector_type(16))) float f32x16;

#define NEGV (-1e9f)

__device__ inline unsigned cvt_bf16(float f) {
    unsigned u = __builtin_bit_cast(unsigned, f);
    u += 0x7FFFu + ((u >> 16) & 1u);   // RNE (no NaNs in this problem)
    return u >> 16;
}
__device__ inline unsigned pk_bf16(float a, float b) {
    return cvt_bf16(a) | (cvt_bf16(b) << 16);
}

__global__ __launch_bounds__(256, 2)
void attn_kernel(const float* __restrict__ Q, const float* __restrict__ K,
                 const float* __restrict__ V, const int* __restrict__ M,
                 float* __restrict__ Out) {
    // pitch 72 shorts (144 B = 36 dwords, 36 mod 32 = 4): row-strided wave
    // accesses spread uniformly over all 32 banks (verified by hand for every
    // access pattern below -> bank-floor, zero conflicts).
    __shared__ __attribute__((aligned(16))) unsigned short sS[256 * 72];  // Q staging, then S tiles (wave-private rows)
    __shared__ __attribute__((aligned(16))) unsigned short sK[64 * 72];
    __shared__ __attribute__((aligned(16))) unsigned short sVt[64 * 72];  // V^T: [d][k]

    const int tid  = threadIdx.x;
    const int wave = tid >> 6;
    const int lane = tid & 63;
    const int half = lane >> 5;
    const int l32  = lane & 31;

    const int bid = blockIdx.x;
    const int h  = bid & 15;            // h innermost: 16 blocks share a mask tile
    const int qt = (bid >> 4) & 7;
    const int b  = bid >> 7;
    const int bh = b * 16 + h;
    const int q0 = qt * 256;

    const float* Qb = Q + (size_t)(bh * 2048 + q0) * 64;
    const float* Kb = K + (size_t)bh * 2048 * 64;
    const float* Vb = V + (size_t)bh * 2048 * 64;
    const int*   Mb = M + (size_t)(b * 2048 + q0) * 2048;

    // ---- stage Q tile (256x64, pre-scaled by 1/sqrt(64)) into sS region ----
#pragma unroll
    for (int i = 0; i < 16; i++) {
        const int e = tid + i * 256, row = e >> 4, c4 = e & 15;
        const float4 v = *(const float4*)(Qb + row * 64 + c4 * 4);
        uint2 p;
        p.x = pk_bf16(v.x * 0.125f, v.y * 0.125f);
        p.y = pk_bf16(v.z * 0.125f, v.w * 0.125f);
        *(uint2*)&sS[row * 72 + c4 * 4] = p;
    }
    __syncthreads();

    // Q fragments live in registers for the whole kernel (B-operand of S^T=K*Q^T).
    // B[k = half*8+j][n = l32] = Q[q0w + l32][dk*16 + half*8 + j]
    bf16x8 qF[2][4];
#pragma unroll
    for (int qb = 0; qb < 2; qb++)
#pragma unroll
        for (int dk = 0; dk < 4; dk++)
            qF[qb][dk] = *(const bf16x8*)&sS[(wave * 64 + qb * 32 + l32) * 72 + dk * 16 + half * 8];

    f32x16 Oacc[2][2];
#pragma unroll
    for (int qb = 0; qb < 2; qb++)
#pragma unroll
        for (int db = 0; db < 2; db++)
#pragma unroll
            for (int r = 0; r < 16; r++) Oacc[qb][db][r] = 0.f;

    for (int ki = 0; ki < 32; ki++) {
        const int k0 = ki * 64;
        __syncthreads();   // prior tile's sK/sVt reads done before overwrite

        // ---- stage K tile [64x64] row-major bf16 ----
#pragma unroll
        for (int i = 0; i < 4; i++) {
            const int e = tid + i * 256, row = e >> 4, c4 = e & 15;
            const float4 kv = *(const float4*)(Kb + (size_t)(k0 + row) * 64 + c4 * 4);
            uint2 p; p.x = pk_bf16(kv.x, kv.y); p.y = pk_bf16(kv.z, kv.w);
            *(uint2*)&sK[row * 72 + c4 * 4] = p;
        }
        // ---- stage V tile transposed: 8 coalesced row loads -> one b128 write ----
#pragma unroll
        for (int i = 0; i < 2; i++) {
            const int kb = (wave * 2 + i) * 8;
            float f[8];
#pragma unroll
            for (int j = 0; j < 8; j++) f[j] = Vb[(size_t)(k0 + kb + j) * 64 + lane];
            uint4 p4;
            p4.x = pk_bf16(f[0], f[1]); p4.y = pk_bf16(f[2], f[3]);
            p4.z = pk_bf16(f[4], f[5]); p4.w = pk_bf16(f[6], f[7]);
            *(uint4*)&sVt[lane * 72 + kb] = p4;
        }
        __syncthreads();

        // ---- MFMA1: S^T[kk 0..63][q 0..63(wave)] = K * Q^T, mask, pack -> sS ----
        // A[m=l32][k=half*8+j] = K[k0+jk*32+l32][dk*16+half*8+j]
        // C layout: col = l32 = q-in-32, row = (reg&3) + 8*(reg>>2) + 4*half = kk-in-32
#pragma unroll
        for (int jk = 0; jk < 2; jk++) {
            bf16x8 aK[4];
#pragma unroll
            for (int dk = 0; dk < 4; dk++)
                aK[dk] = *(const bf16x8*)&sK[(jk * 32 + l32) * 72 + dk * 16 + half * 8];
#pragma unroll
            for (int qb = 0; qb < 2; qb++) {
                f32x16 acc;
#pragma unroll
                for (int r = 0; r < 16; r++) acc[r] = 0.f;
#pragma unroll
                for (int dk = 0; dk < 4; dk++)
                    acc = __builtin_amdgcn_mfma_f32_32x32x16_bf16(aK[dk], qF[qb][dk], acc, 0, 0, 0);
                const int qrow = wave * 64 + qb * 32 + l32;           // tile-local q
                const int kcol = k0 + jk * 32 + half * 4;             // global kk base
#pragma unroll
                for (int rg = 0; rg < 4; rg++) {
                    const int4 mm = *(const int4*)&Mb[(size_t)qrow * 2048 + kcol + rg * 8];
                    const float v0 = mm.x ? NEGV : acc[rg * 4 + 0];
                    const float v1 = mm.y ? NEGV : acc[rg * 4 + 1];
                    const float v2 = mm.z ? NEGV : acc[rg * 4 + 2];
                    const float v3 = mm.w ? NEGV : acc[rg * 4 + 3];
                    uint2 p; p.x = pk_bf16(v0, v1); p.y = pk_bf16(v2, v3);
                    // wave-private rows: no barrier needed (same-wave DS ops in order)
                    *(uint2*)&sS[qrow * 72 + jk * 32 + rg * 8 + half * 4] = p;
                }
            }
        }

        // ---- MFMA2: O[q][d] += S @ V ----
        // A[m=l32][k=half*8+j] = S[q][kkb*16+half*8+j]  (from wave-private sS)
        // B[k=half*8+j][n=l32] = V[kkb*16+half*8+j][db*32+l32] (from sVt)
#pragma unroll
        for (int kkb = 0; kkb < 4; kkb++) {
            bf16x8 bV[2];
#pragma unroll
            for (int db = 0; db < 2; db++)
                bV[db] = *(const bf16x8*)&sVt[(db * 32 + l32) * 72 + kkb * 16 + half * 8];
#pragma unroll
            for (int qb = 0; qb < 2; qb++) {
                const bf16x8 aS = *(const bf16x8*)&sS[(wave * 64 + qb * 32 + l32) * 72 + kkb * 16 + half * 8];
#pragma unroll
                for (int db = 0; db < 2; db++)
                    Oacc[qb][db] = __builtin_amdgcn_mfma_f32_32x32x16_bf16(aS, bV[db], Oacc[qb][db], 0, 0, 0);
            }
        }
    }

    // ---- epilogue: log_softmax over d=64 ----
    // Oacc: row q-in-32 = (r&3)+8*(r>>2)+4*half, col d = db*32 + l32.
    // Full d-row = 32 lanes (l32) x 2 db regs within one half -> xor 1..16.
    float* Ob = Out + (size_t)bh * 2048 * 64;
#pragma unroll
    for (int qb = 0; qb < 2; qb++) {
#pragma unroll
        for (int r = 0; r < 16; r++) {
            const float v0 = Oacc[qb][0][r], v1 = Oacc[qb][1][r];
            float mx = fmaxf(v0, v1);
#pragma unroll
            for (int off = 1; off < 32; off <<= 1)
                mx = fmaxf(mx, __shfl_xor(mx, off, 64));
            float s = __expf(v0 - mx) + __expf(v1 - mx);
#pragma unroll
            for (int off = 1; off < 32; off <<= 1)
                s += __shfl_xor(s, off, 64);
            const float lse = mx + __logf(s);
            const int qrow = q0 + wave * 64 + qb * 32 + (r & 3) + 8 * (r >> 2) + 4 * half;
            Ob[(size_t)qrow * 64 + l32]      = v0 - lse;
            Ob[(size_t)qrow * 64 + 32 + l32] = v1 - lse;
        }
    }
}

extern "C" void kernel_launch(void* const* d_in, const int* in_sizes, int n_in,
                              void* d_out, int out_size, void* d_ws, size_t ws_size,
                              hipStream_t stream) {
    const float* Q = (const float*)d_in[0];
    const float* K = (const float*)d_in[1];
    const float* V = (const float*)d_in[2];
    const int*   M = (const int*)d_in[3];
    float* Out = (float*)d_out;

    dim3 grid(512);    // 4*16 bh * 8 q-tiles; 2 blocks/CU -> fully resident
    dim3 block(256);
    attn_kernel<<<grid, block, 0, stream>>>(Q, K, V, M, Out);
}